// Round 6
// baseline (190.170 us; speedup 1.0000x reference)
//
#include <hip/hip_runtime.h>
#include <climits>

#define HW 262144          // 512*512
#define IW 512
#define RN 725             // rotated canvas side (virtual)
#define NSEG 256
#define CH_OFF 1536
#define TH_OFF 116736
#define XY_OFF 485376
#define NBLK 1024          // blocks per image in k_grad
#define THP 16             // pixel splits in k_thist

static __device__ __forceinline__ float loadpix(const float* p, int y, int x, int n) {
    return (y >= 0 && y < n && x >= 0 && x < n) ? p[y * n + x] : 0.0f;
}

// virtual rot-canvas sample: canvas coord (cx,cy) -> nearest img pixel (exact rot formula)
static __device__ __forceinline__ float rtap(const float* __restrict__ im, int cx, int cy) {
    if (cx < 0 || cx >= RN || cy < 0 || cy >= RN) return 0.f;   // canvas zero-pad
    const float cs = 0.7071067811865476f;
    float xg = (float)cx - 362.0f;          // (725-1)/2
    float yg = (float)cy - 362.0f;
    float xi = cs * xg - cs * yg + 255.5f;  // c*xg - s*yg + (W-1)/2
    float yi = cs * xg + cs * yg + 255.5f;
    int xn = (int)rintf(xi);
    int yn = (int)rintf(yi);
    if (xn < 0 || xn >= IW || yn < 0 || yn >= IW) return 0.f;   // img zero (invalid)
    return im[yn * IW + xn];
}

// ---- fused: straight Scharr + virtual-rotated Scharr + min/max partials + bb init ----
__global__ void k_grad(const float* __restrict__ img, float* __restrict__ g,
                       float* __restrict__ grc, float* __restrict__ pmin,
                       float* __restrict__ pmax, int* __restrict__ bb) {
    int p = blockIdx.x * blockDim.x + threadIdx.x;
    int bc = blockIdx.y;
    int tid = threadIdx.x;
    // fold bbox init into first 6 blocks of plane 0
    if (blockIdx.y == 0 && blockIdx.x < 6) {
        int i = blockIdx.x * 256 + tid;
        bb[i] = INT_MAX;            // xmin
        bb[1536 + i] = INT_MIN;     // xmax
        bb[3072 + i] = INT_MAX;     // ymin
        bb[4608 + i] = INT_MIN;     // ymax
    }
    int y = p >> 9, x = p & 511;
    const float* im = img + (size_t)bc * HW;
    // straight Scharr
    float a = loadpix(im, y - 1, x - 1, IW), b = loadpix(im, y - 1, x, IW), c = loadpix(im, y - 1, x + 1, IW);
    float d = loadpix(im, y, x - 1, IW), e = loadpix(im, y, x + 1, IW);
    float f = loadpix(im, y + 1, x - 1, IW), h = loadpix(im, y + 1, x, IW), i9 = loadpix(im, y + 1, x + 1, IW);
    float g0 = -3.f * a + 3.f * c + 10.f * d + 10.f * e - 3.f * f + 3.f * i9;
    float g1 = -3.f * a + 10.f * b - 3.f * c + 3.f * f + 10.f * h + 3.f * i9;
    g[((size_t)bc * 2 + 0) * HW + p] = g0;
    g[((size_t)bc * 2 + 1) * HW + p] = g1;
    // diagonal (virtual rotate -> scharr -> rotate-back -> crop)
    const float cs = 0.7071067811865476f;  // cos(-45); sin(-45) = -cs
    float xg = (float)(x + 105) - 512.5f;  // (1026-1)/2
    float yg = (float)(y + 105) - 512.5f;
    float t1 = cs * xg, t2 = cs * yg;
    float xi = (t1 + t2) + 362.0f;
    float yi = (-t1 + t2) + 362.0f;
    int xn = (int)rintf(xi);
    int yn = (int)rintf(yi);
    float r0 = 0.f, r1 = 0.f;
    if (xn >= 0 && xn < RN && yn >= 0 && yn < RN) {
        float ra = rtap(im, xn - 1, yn - 1), rb = rtap(im, xn, yn - 1), rc = rtap(im, xn + 1, yn - 1);
        float rd = rtap(im, xn - 1, yn),     re = rtap(im, xn + 1, yn);
        float rf = rtap(im, xn - 1, yn + 1), rh = rtap(im, xn, yn + 1), ri = rtap(im, xn + 1, yn + 1);
        r0 = -3.f * ra + 3.f * rc + 10.f * rd + 10.f * re - 3.f * rf + 3.f * ri;
        r1 = -3.f * ra + 10.f * rb - 3.f * rc + 3.f * rf + 10.f * rh + 3.f * ri;
    }
    grc[((size_t)bc * 2 + 0) * HW + p] = r0;
    grc[((size_t)bc * 2 + 1) * HW + p] = r1;
    // combined 4-value min/max block reduce -> per-block partials
    __shared__ float slo[4][256], shi[4][256];
    slo[0][tid] = g0; shi[0][tid] = g0;
    slo[1][tid] = g1; shi[1][tid] = g1;
    slo[2][tid] = r0; shi[2][tid] = r0;
    slo[3][tid] = r1; shi[3][tid] = r1;
    __syncthreads();
    for (int off = 128; off > 0; off >>= 1) {
        if (tid < off) {
            #pragma unroll
            for (int k = 0; k < 4; ++k) {
                slo[k][tid] = fminf(slo[k][tid], slo[k][tid + off]);
                shi[k][tid] = fmaxf(shi[k][tid], shi[k][tid + off]);
            }
        }
        __syncthreads();
    }
    if (tid == 0) {
        int bx = blockIdx.x;
        int m0 = bc * 2, m1 = bc * 2 + 1, m2 = 12 + bc * 2, m3 = 12 + bc * 2 + 1;
        pmin[m0 * NBLK + bx] = slo[0][0]; pmax[m0 * NBLK + bx] = shi[0][0];
        pmin[m1 * NBLK + bx] = slo[1][0]; pmax[m1 * NBLK + bx] = shi[1][0];
        pmin[m2 * NBLK + bx] = slo[2][0]; pmax[m2 * NBLK + bx] = shi[2][0];
        pmin[m3 * NBLK + bx] = slo[3][0]; pmax[m3 * NBLK + bx] = shi[3][0];
    }
}

// ---- stage-2: reduce 1024 partials per map -> mm[m*2], mm[m*2+1] ----
__global__ void k_mmreduce(const float* __restrict__ pmin, const float* __restrict__ pmax,
                           float* __restrict__ mm) {
    int m = blockIdx.x;
    int tid = threadIdx.x;
    float lo = 3.4e38f, hi = -3.4e38f;
    for (int i = tid; i < NBLK; i += 256) {
        lo = fminf(lo, pmin[m * NBLK + i]);
        hi = fmaxf(hi, pmax[m * NBLK + i]);
    }
    __shared__ float slo[256], shi[256];
    slo[tid] = lo; shi[tid] = hi;
    __syncthreads();
    for (int off = 128; off > 0; off >>= 1) {
        if (tid < off) {
            slo[tid] = fminf(slo[tid], slo[tid + off]);
            shi[tid] = fmaxf(shi[tid], shi[tid + off]);
        }
        __syncthreads();
    }
    if (tid == 0) { mm[m * 2] = slo[0]; mm[m * 2 + 1] = shi[0]; }
}

// ---- fused color histogram + (c==0) region sizes & bbox ----
// gy = bg*3 + c ; all blocks: 6400-bin chist; c==0 blocks also region+bbox
__global__ void k_regchist(const float* __restrict__ img, const int* __restrict__ lab,
                           float* __restrict__ rs_out, int* __restrict__ bb,
                           float* __restrict__ ch_out) {
    __shared__ unsigned cnt[NSEG * 25];
    __shared__ unsigned rcnt[NSEG];
    __shared__ int sxmin[NSEG], sxmax[NSEG], symin[NSEG], symax[NSEG];
    int gy = blockIdx.y;       // (b*3+g)*3 + c
    int c = gy % 3;
    int bg = gy / 3;           // b*3+g
    int b = bg / 3;
    bool do_reg = (c == 0);
    for (int i = threadIdx.x; i < NSEG * 25; i += blockDim.x) cnt[i] = 0;
    if (do_reg) {
        for (int i = threadIdx.x; i < NSEG; i += blockDim.x) {
            rcnt[i] = 0; sxmin[i] = INT_MAX; sxmax[i] = INT_MIN;
            symin[i] = INT_MAX; symax[i] = INT_MIN;
        }
    }
    __syncthreads();
    const float4* ip = (const float4*)(img + ((size_t)b * 3 + c) * HW);
    const int4* lp = (const int4*)(lab + (size_t)bg * HW);
    int stride = blockDim.x * gridDim.x;
    for (int i = blockIdx.x * blockDim.x + threadIdx.x; i < HW / 4; i += stride) {
        float4 v4 = ip[i];
        int4 l4 = lp[i];
        int l0 = l4.x & 255, l1 = l4.y & 255, l2 = l4.z & 255, l3 = l4.w & 255;
        int b0 = (int)((float)l0 * 25.0f + v4.x * 24.0f);
        int b1 = (int)((float)l1 * 25.0f + v4.y * 24.0f);
        int b2 = (int)((float)l2 * 25.0f + v4.z * 24.0f);
        int b3 = (int)((float)l3 * 25.0f + v4.w * 24.0f);
        b0 = min(max(b0, 0), NSEG * 25 - 1); b1 = min(max(b1, 0), NSEG * 25 - 1);
        b2 = min(max(b2, 0), NSEG * 25 - 1); b3 = min(max(b3, 0), NSEG * 25 - 1);
        atomicAdd(&cnt[b0], 1u); atomicAdd(&cnt[b1], 1u);
        atomicAdd(&cnt[b2], 1u); atomicAdd(&cnt[b3], 1u);
        if (do_reg) {
            int p = i << 2;
            int y = p >> 9, x = p & 511;
            atomicAdd(&rcnt[l0], 1u); atomicAdd(&rcnt[l1], 1u);
            atomicAdd(&rcnt[l2], 1u); atomicAdd(&rcnt[l3], 1u);
            atomicMin(&sxmin[l0], x);     atomicMax(&sxmax[l0], x);
            atomicMin(&sxmin[l1], x + 1); atomicMax(&sxmax[l1], x + 1);
            atomicMin(&sxmin[l2], x + 2); atomicMax(&sxmax[l2], x + 2);
            atomicMin(&sxmin[l3], x + 3); atomicMax(&sxmax[l3], x + 3);
            atomicMin(&symin[l0], y); atomicMax(&symax[l0], y);
            atomicMin(&symin[l1], y); atomicMax(&symax[l1], y);
            atomicMin(&symin[l2], y); atomicMax(&symax[l2], y);
            atomicMin(&symin[l3], y); atomicMax(&symax[l3], y);
        }
    }
    __syncthreads();
    for (int i = threadIdx.x; i < NSEG * 25; i += blockDim.x) {
        unsigned n = cnt[i];
        if (n) {
            int s = i / 25, cb = i - s * 25;
            atomicAdd(&ch_out[((size_t)(bg * NSEG + s) * 3 + c) * 25 + cb], (float)n);
        }
    }
    if (do_reg) {
        for (int i = threadIdx.x; i < NSEG; i += blockDim.x) {
            if (rcnt[i]) atomicAdd(&rs_out[bg * NSEG + i], (float)rcnt[i]);
            if (sxmin[i] != INT_MAX) {
                atomicMin(&bb[bg * NSEG + i], sxmin[i]);
                atomicMax(&bb[1536 + bg * NSEG + i], sxmax[i]);
                atomicMin(&bb[3072 + bg * NSEG + i], symin[i]);
                atomicMax(&bb[4608 + bg * NSEG + i], symax[i]);
            }
        }
    }
}

// ---- texture histogram: block = (bc,d,base,gi), pos+neg hists together ----
// gy = ((bc*2 + d)*2 + base)*3 + gi ; writes u32 partials (no atomics)
__global__ void k_thist(const float* __restrict__ maps, const int* __restrict__ lab,
                        const float* __restrict__ mm, unsigned* __restrict__ thp) {
    __shared__ unsigned cnt[2 * 2560];  // [0,2560): pos, [2560,5120): neg
    int gy = blockIdx.y;
    int gi = gy % 3;
    int r = gy / 3;
    int base = r & 1;
    int bd = r >> 1;
    int d = bd & 1;
    int bc = bd >> 1;
    int b = bc / 3;
    int m = base * 12 + bc * 2 + d;
    for (int i = threadIdx.x; i < 5120; i += 256) cnt[i] = 0;
    __syncthreads();
    float mn = mm[m * 2], mx = mm[m * 2 + 1];
    float hminp = fmaxf(mn, 0.f);
    float denp = fmaxf(mx, 0.f) - hminp;
    float hminn = fminf(mn, 0.f);
    float denn = fminf(mx, 0.f) - hminn;
    const float4* src = (const float4*)(maps + (size_t)m * HW);
    const int4* lp = (const int4*)(lab + (size_t)(b * 3 + gi) * HW);
    int stride = blockDim.x * gridDim.x;
    for (int i = blockIdx.x * blockDim.x + threadIdx.x; i < HW / 4; i += stride) {
        float4 v4 = src[i];
        int4 l4 = lp[i];
#define TH_ONE(V, L)                                                        \
        {                                                                   \
            float v = (V);                                                  \
            float la = (float)((L) & 255);                                  \
            float tp = ((fmaxf(v, 0.f) - hminp) / denp) * 9.0f;             \
            float tn = ((fminf(v, 0.f) - hminn) / denn) * 9.0f;             \
            int bp = (int)(la * 10.0f + tp);                                \
            int bn = (int)(la * 10.0f + tn);                                \
            bp = min(max(bp, 0), 2559);                                     \
            bn = min(max(bn, 0), 2559);                                     \
            atomicAdd(&cnt[bp], 1u);                                        \
            atomicAdd(&cnt[2560 + bn], 1u);                                 \
        }
        TH_ONE(v4.x, l4.x) TH_ONE(v4.y, l4.y) TH_ONE(v4.z, l4.z) TH_ONE(v4.w, l4.w)
#undef TH_ONE
    }
    __syncthreads();
    unsigned* dst = thp + ((size_t)gy * THP + blockIdx.x) * 5120;
    for (int i = threadIdx.x; i < 5120; i += 256) dst[i] = cnt[i];
}

// ---- sum THP partials per (gy,bin) and scatter to th layout (B,I,G,S,C,8,10) ----
__global__ void k_threduce(const unsigned* __restrict__ thp, float* __restrict__ th_out) {
    int gy = blockIdx.x;   // 72
    int gi = gy % 3;
    int r = gy / 3;
    int base = r & 1;
    int bd = r >> 1;
    int d = bd & 1;
    int bc = bd >> 1;
    int b = bc / 3, c = bc - b * 3;
    for (int i = threadIdx.x; i < 5120; i += 256) {
        unsigned s = 0;
        for (int p = 0; p < THP; ++p) s += thp[((size_t)gy * THP + p) * 5120 + i];
        int pos = (i < 2560);
        int rr = pos ? i : i - 2560;
        int seg = rr / 10, tb = rr - seg * 10;
        int t = base * 4 + (pos ? 0 : 2) + d;
        size_t idx = ((size_t)((b * 3 + gi) * NSEG + seg) * 3 + c) * 80 + t * 10 + tb;
        th_out[idx] = (float)s;
    }
}

// ---- normalize ch/th and write xywh ----
__global__ void k_final(float* __restrict__ out, const int* __restrict__ bb) {
    int seg = blockIdx.x;   // big*256 + s, 1536 total
    float rs = out[seg];
    float cd = 3.0f * rs;
    float td = 24.0f * rs;
    float* ch = out + CH_OFF + (size_t)seg * 75;
    float* th = out + TH_OFF + (size_t)seg * 240;
    for (int i = threadIdx.x; i < 75; i += blockDim.x) ch[i] = ch[i] / cd;
    for (int i = threadIdx.x; i < 240; i += blockDim.x) th[i] = th[i] / td;
    if (threadIdx.x == 0) {
        int xmin, xmax, ymin, ymax;
        if (rs > 0.f) {
            xmin = bb[seg]; xmax = bb[1536 + seg];
            ymin = bb[3072 + seg]; ymax = bb[4608 + seg];
        } else {
            xmin = IW; ymin = IW; xmax = 0; ymax = 0;
        }
        float* xy = out + XY_OFF + (size_t)seg * 4;
        xy[0] = (float)xmin; xy[1] = (float)ymin;
        xy[2] = (float)(xmax - xmin); xy[3] = (float)(ymax - ymin);
    }
}

extern "C" void kernel_launch(void* const* d_in, const int* in_sizes, int n_in,
                              void* d_out, int out_size, void* d_ws, size_t ws_size,
                              hipStream_t stream) {
    const float* img = (const float*)d_in[0];
    const int* lab = (const int*)d_in[1];
    float* out = (float*)d_out;

    float* ws = (float*)d_ws;
    float* gmaps = ws;                            // 12 maps * 262144
    float* grcmaps = gmaps + (size_t)12 * HW;     // 12 maps (contiguous after g)
    float* pmin = grcmaps + (size_t)12 * HW;      // 24*1024
    float* pmax = pmin + 24 * NBLK;               // 24*1024
    float* mm = pmax + 24 * NBLK;                 // 48 floats
    int* bb = (int*)(mm + 48);                    // 4*1536 ints
    unsigned* thp = (unsigned*)(bb + 4 * 1536);   // 72*THP*5120 u32 (~23.6 MB)

    hipMemsetAsync(d_out, 0, (size_t)out_size * sizeof(float), stream);
    hipLaunchKernelGGL(k_grad, dim3(NBLK, 6), dim3(256), 0, stream, img, gmaps, grcmaps, pmin, pmax, bb);
    hipLaunchKernelGGL(k_mmreduce, dim3(24), dim3(256), 0, stream, pmin, pmax, mm);
    hipLaunchKernelGGL(k_regchist, dim3(32, 18), dim3(256), 0, stream, img, lab, out, bb, out + CH_OFF);
    hipLaunchKernelGGL(k_thist, dim3(THP, 72), dim3(256), 0, stream, gmaps, lab, mm, thp);
    hipLaunchKernelGGL(k_threduce, dim3(72), dim3(256), 0, stream, thp, out + TH_OFF);
    hipLaunchKernelGGL(k_final, dim3(1536), dim3(64), 0, stream, out, bb);
}